// Round 5
// baseline (109.975 us; speedup 1.0000x reference)
//
#include <hip/hip_runtime.h>
#include <hip/hip_bf16.h>

// TripletBatchHardLoss: N=8192, D=256, fp32 embeddings (L2-normalized), int32 labels.
// Normalized -> pdist monotone DECREASING in dot:
//   hard_negative = max dot over negs, hard_positive = min dot over poss (diag dot~1 safe).
// R20 = R19 resubmit (container-level infra failure, no counters; kernel audit found no
// deadlock path: zero barriers, counted drainable waitcnts, valid launch config).
// FULLY INDEPENDENT WAVES: 8256 single-wave (64-thread) blocks, one 64x64 output
// tile per wave, wave-private dbuf LDS (16 KB/block -> 10 blocks/CU), ZERO barriers.
//   - R15-R18 evidence: perf tracks independent co-resident waves (12 coupled waves =
//     44.9us, 8 = 56.6us, 0-LDS = 78us); barrier surgery inside a lockstep block bought
//     only ~5% (R18 tile <=42.5us). So remove wave coupling entirely.
//   - Single-wave correctness needs no s_barrier: DMA for kt+1 is issued after the
//     lgkmcnt-guarded ds_reads of body kt-1 (program order) -> WAR-safe on the 2-buffer;
//     vmcnt(8) drains own kt-batch while kt+1's 8 DMAs stay in flight (counted, never 0
//     mid-loop). Epilogue LDS combine is same-wave: DS ops are in-order per wave, and
//     the lgkmcnt(0) fence guards write->read; no syncthreads.
//   - Per-wave work identical to R15's per-wave share (128 MFMAs, 64 ds_read_b128,
//     verified chunk-XOR swizzle, m89 C/D layout, DPP/shfl reductions); staging is
//     duplicated per wave (2x L2 traffic ~530MB ~ 12TB/s, well under 34.5 ceiling).
//   - 4 atomic wave-instrs per wave (R15 atomic-tail lesson: instruction count, not
//     address contention, is what serializes retirement).
// VGPR discipline: launch_bounds(64,3) caps at 168 (acc 64 AGPR + frags 32 + addr ~30).
// No __threadfence in wide kernels (R11: per-block fence = per-XCD L2 writeback, +130 us).

#define NS 8192
#define DD 256
#define NT 8256   // 128*129/2 triangle over 64-row groups
#define EPS_PD 1e-12f
#define BIGF 1e30f

typedef unsigned short u16;
typedef unsigned int u32;
typedef short short8 __attribute__((ext_vector_type(8)));
typedef float f32x4 __attribute__((ext_vector_type(4)));

typedef const __attribute__((address_space(1))) u32 glb_u32;
typedef __attribute__((address_space(3))) u32 lds_u32;

__device__ __forceinline__ void async16(const void* g, void* l) {
    __builtin_amdgcn_global_load_lds((glb_u32*)g, (lds_u32*)l, 16, 0, 0);
}

// order-preserving float <-> uint key (unsigned compare == float compare)
__device__ __forceinline__ u32 fkey(float f) {
    u32 b = __float_as_uint(f);
    return (b & 0x80000000u) ? ~b : (b | 0x80000000u);
}
__device__ __forceinline__ float unkey(u32 k) {
    u32 b = (k & 0x80000000u) ? (k ^ 0x80000000u) : ~k;
    return __uint_as_float(b);
}

__device__ __forceinline__ u16 f2bf_rne(float f) {
    u32 b = __float_as_uint(f);
    b += 0x7FFFu + ((b >> 16) & 1u);
    return (u16)(b >> 16);
}

// DPP lane-move within 16-lane rows (reduction groups are exactly DPP rows)
template <int CTRL>
__device__ __forceinline__ float dpp_mov(float x) {
    return __int_as_float(
        __builtin_amdgcn_update_dpp(0, __float_as_int(x), CTRL, 0xF, 0xF, true));
}

// ---------------- kernel 1: fp32 -> bf16, row sum-of-squares, init keys ----------------
__global__ __launch_bounds__(256) void prep_kernel(
    const float* __restrict__ e, u16* __restrict__ ebf, float* __restrict__ sq,
    u32* __restrict__ mxk, u32* __restrict__ mnk, float* __restrict__ out) {
    const int tid = blockIdx.x * 256 + threadIdx.x;   // 2048 blocks
    const int row = tid >> 6, t = tid & 63;           // one wave per row
    float4 v = ((const float4*)(e + (size_t)row * DD))[t];
    ushort4 u;
    u.x = f2bf_rne(v.x); u.y = f2bf_rne(v.y); u.z = f2bf_rne(v.z); u.w = f2bf_rne(v.w);
    ((ushort4*)(ebf + (size_t)row * DD))[t] = u;
    float s = v.x * v.x + v.y * v.y + v.z * v.z + v.w * v.w;
    for (int o = 32; o; o >>= 1) s += __shfl_down(s, o);
    if (t == 0) {
        sq[row] = s;
        mxk[row] = 0u;            // sentinel for unsigned max
        mnk[row] = 0xFFFFFFFFu;   // sentinel for unsigned min
        if (row == 0) out[0] = 0.0f;
    }
}

// ------------- kernel 2: single-wave 64x64 dot-tiles + two-sided masked reduction --------
__global__ __launch_bounds__(64, 3) void tile_kernel(
    const u16* __restrict__ ebf, const int* __restrict__ labels,
    u32* __restrict__ mxk, u32* __restrict__ mnk) {
    // per-wave tiles: 64 rows x 32 u16 (4 KB) each; 16B chunk (row,c) at
    // slot row*4 + (c ^ ((row>>2)&3))  -> 2-way bank alias on ds_read_b128 (free, m136)
    __shared__ __attribute__((aligned(16))) u16 lds_a[2][2048];   // 2 x 4 KB
    __shared__ __attribute__((aligned(16))) u16 lds_b[2][2048];   // 2 x 4 KB

    // decode linear triangle index -> (i <= j) over 128 row-groups of 64
    const int t = blockIdx.x;
    int j = (int)((sqrtf(8.0f * (float)t + 1.0f) - 1.0f) * 0.5f);
    while ((j + 1) * (j + 2) / 2 <= t) ++j;
    while (j * (j + 1) / 2 > t) --j;
    const int i = t - j * (j + 1) / 2;
    const int bi = i * 64, bj = j * 64;

    const int lane = threadIdx.x & 63;
    const int l15 = lane & 15, q = lane >> 4;

    // staging sources: 4 DMAs per tile per kt; DMA p covers slots [p*64, p*64+64),
    // slot s: row = s>>2, chunk = (s&3) ^ ((row>>2)&3) (pre-swizzled global source)
    const u16* gA[4];
    const u16* gB[4];
#pragma unroll
    for (int p = 0; p < 4; ++p) {
        const int s = p * 64 + lane;
        const int r = s >> 2, c = (s & 3) ^ ((r >> 2) & 3);
        gA[p] = ebf + (size_t)(bi + r) * DD + c * 8;
        gB[p] = ebf + (size_t)(bj + r) * DD + c * 8;
    }

    // frag-read offsets (u16): row = mi*16 + l15, chunk q -> slot row*4 + (q^((row>>2)&3));
    // mi*16 rows contribute mi*4 to (row>>2), == 0 mod 4, so swz depends on l15 only.
    const int swz = (q ^ (l15 >> 2)) * 8;
    const int offa = l15 * 32 + swz;   // + mi*512
    const int offb = l15 * 32 + swz;   // + ni*512

#define ISSUE_TILE(buf, ko)                                     \
    do {                                                        \
        async16(gA[0] + (ko), &lds_a[buf][0]);                  \
        async16(gA[1] + (ko), &lds_a[buf][512]);                \
        async16(gA[2] + (ko), &lds_a[buf][1024]);               \
        async16(gA[3] + (ko), &lds_a[buf][1536]);               \
        async16(gB[0] + (ko), &lds_b[buf][0]);                  \
        async16(gB[1] + (ko), &lds_b[buf][512]);                \
        async16(gB[2] + (ko), &lds_b[buf][1024]);               \
        async16(gB[3] + (ko), &lds_b[buf][1536]);               \
    } while (0)

    // prologue: kt0 into buffer 0 (8 DMAs in flight)
    ISSUE_TILE(0, 0);

    f32x4 acc[4][4] = {};
#pragma unroll
    for (int kt = 0; kt < 8; ++kt) {
        const int cur = kt & 1;   // static after full unroll
        if (kt < 7) {
            // issue kt+1 into the other buffer BEFORE draining kt (issue-before-wait).
            // WAR-safe within this single wave: body kt-1's ds_reads from buf[cur^1]
            // completed (lgkmcnt-guarded before its MFMAs) before these issue in
            // program order. Then drain exactly kt's 8 DMAs, keep kt+1's 8 in flight.
            ISSUE_TILE(cur ^ 1, (kt + 1) * 32);
            asm volatile("s_waitcnt vmcnt(8)" ::: "memory");
        } else {
            asm volatile("s_waitcnt vmcnt(0)" ::: "memory");
        }
        short8 af[4], bfr[4];
#pragma unroll
        for (int mi = 0; mi < 4; ++mi)
            af[mi] = *(const short8*)(&lds_a[cur][offa + mi * 512]);
#pragma unroll
        for (int ni = 0; ni < 4; ++ni)
            bfr[ni] = *(const short8*)(&lds_b[cur][offb + ni * 512]);
#pragma unroll
        for (int mi = 0; mi < 4; ++mi)
#pragma unroll
            for (int ni = 0; ni < 4; ++ni)
                acc[mi][ni] = __builtin_amdgcn_mfma_f32_16x16x32_bf16(
                    af[mi], bfr[ni], acc[mi][ni], 0, 0, 0);
        // no barriers: single wave; compiler emits fine-grained lgkmcnt for ds->MFMA
    }

    // ---- epilogue: C/D layout col = lane&15, row = q*4 + reg (m89-verified) ----
    // output rows bi + mi*16 + q*4 + r2; cols bj + ni*16 + l15
    int li[4][4];
#pragma unroll
    for (int mi = 0; mi < 4; ++mi) {
        const int4 v = *(const int4*)(labels + bi + mi * 16 + q * 4);
        li[mi][0] = v.x; li[mi][1] = v.y; li[mi][2] = v.z; li[mi][3] = v.w;
    }
    int lj[4];
#pragma unroll
    for (int ni = 0; ni < 4; ++ni) lj[ni] = labels[bj + ni * 16 + l15];

    float mxn[4][4], mnp[4][4];                        // row-side per (mi, r)
    float mxc[4] = {-BIGF, -BIGF, -BIGF, -BIGF};       // col-side per ni
    float mnc[4] = {BIGF, BIGF, BIGF, BIGF};
#pragma unroll
    for (int mi = 0; mi < 4; ++mi)
#pragma unroll
        for (int r2 = 0; r2 < 4; ++r2) { mxn[mi][r2] = -BIGF; mnp[mi][r2] = BIGF; }

#pragma unroll
    for (int mi = 0; mi < 4; ++mi)
#pragma unroll
        for (int ni = 0; ni < 4; ++ni) {
            const int l = lj[ni];
#pragma unroll
            for (int r2 = 0; r2 < 4; ++r2) {
                const float d = acc[mi][ni][r2];
                const bool same = (li[mi][r2] == l);
                const float sneg = same ? -BIGF : d;
                const float spos = same ? d : BIGF;
                mxn[mi][r2] = fmaxf(mxn[mi][r2], sneg);
                mnp[mi][r2] = fminf(mnp[mi][r2], spos);
                mxc[ni] = fmaxf(mxc[ni], sneg);
                mnc[ni] = fminf(mnc[ni], spos);
            }
        }

    // col-side: reduce over q (lanes l15, +16, +32, +48) via shfl_xor 16/32
#pragma unroll
    for (int ni = 0; ni < 4; ++ni) {
        mxc[ni] = fmaxf(mxc[ni], __shfl_xor(mxc[ni], 16));
        mnc[ni] = fminf(mnc[ni], __shfl_xor(mnc[ni], 16));
        mxc[ni] = fmaxf(mxc[ni], __shfl_xor(mxc[ni], 32));
        mnc[ni] = fminf(mnc[ni], __shfl_xor(mnc[ni], 32));
    }
    // row-side: 16-lane DPP reduction (xor1, xor2, ror4, ror8)
#pragma unroll
    for (int mi = 0; mi < 4; ++mi)
#pragma unroll
        for (int r2 = 0; r2 < 4; ++r2) {
            float x = mxn[mi][r2], n = mnp[mi][r2];
            x = fmaxf(x, dpp_mov<0xB1>(x));  n = fminf(n, dpp_mov<0xB1>(n));
            x = fmaxf(x, dpp_mov<0x4E>(x));  n = fminf(n, dpp_mov<0x4E>(n));
            x = fmaxf(x, dpp_mov<0x124>(x)); n = fminf(n, dpp_mov<0x124>(n));
            x = fmaxf(x, dpp_mov<0x128>(x)); n = fminf(n, dpp_mov<0x128>(n));
            mxn[mi][r2] = x; mnp[mi][r2] = n;
        }

    // ---- same-wave LDS redistribute -> 4 atomic wave-instrs ----
    // scratch reuses lds_a[0] (body 7 read buffer 1 only; DS ops are in-order per wave,
    // so these writes follow all earlier buf-0 reads).
    // Layout (floats): [0..63] rowmax, [64..127] rowmin, [128..191] colmax, [192..255] colmin.
    float* red = (float*)&lds_a[0][0];
    if (l15 == 0) {
#pragma unroll
        for (int mi = 0; mi < 4; ++mi)
#pragma unroll
            for (int r2 = 0; r2 < 4; ++r2) {
                const int rl = mi * 16 + q * 4 + r2;
                red[rl] = mxn[mi][r2];
                red[64 + rl] = mnp[mi][r2];
            }
    }
    if (q == 0) {
#pragma unroll
        for (int ni = 0; ni < 4; ++ni) {
            const int cl = ni * 16 + l15;
            red[128 + cl] = mxc[ni];
            red[192 + cl] = mnc[ni];
        }
    }
    // same-wave ds_write -> ds_read ordering: drain LDS queue, block compiler reordering
    asm volatile("s_waitcnt lgkmcnt(0)" ::: "memory");
    const float rmx = red[lane];
    const float rmn = red[64 + lane];
    const float cmx = red[128 + lane];
    const float cmn = red[192 + lane];
    atomicMax(&mxk[bi + lane], fkey(rmx));
    atomicMin(&mnk[bi + lane], fkey(rmn));
    atomicMax(&mxk[bj + lane], fkey(cmx));
    atomicMin(&mnk[bj + lane], fkey(cmn));
}

// ---------------- kernel 3: per-row loss + mean ----------------
__global__ __launch_bounds__(256) void finalize_kernel(
    const u32* __restrict__ mxk, const u32* __restrict__ mnk,
    const float* __restrict__ sq, float* __restrict__ out) {
    const int i = blockIdx.x * 256 + threadIdx.x;
    const float s = sq[i] + 1.0f;   // sq_i + sq_j, sq_j = 1 +- 1e-7
    const float hn = sqrtf(fmaxf(fmaf(-2.0f, unkey(mxk[i]), s), EPS_PD));
    const float hp = sqrtf(fmaxf(fmaf(-2.0f, unkey(mnk[i]), s), EPS_PD));
    float loss = fmaxf(hp - hn + 1.0f, 0.0f);
    for (int o = 32; o; o >>= 1) loss += __shfl_down(loss, o);
    __shared__ float wsum[4];
    const int lane = threadIdx.x & 63, w = threadIdx.x >> 6;
    if (lane == 0) wsum[w] = loss;
    __syncthreads();
    if (threadIdx.x == 0)
        atomicAdd(out, (wsum[0] + wsum[1] + wsum[2] + wsum[3]) * (1.0f / NS));
}

extern "C" void kernel_launch(void* const* d_in, const int* in_sizes, int n_in,
                              void* d_out, int out_size, void* d_ws, size_t ws_size,
                              hipStream_t stream) {
    const int* labels = (const int*)d_in[0];
    const float* emb = (const float*)d_in[1];
    float* out = (float*)d_out;

    char* ws = (char*)d_ws;
    u16* ebf = (u16*)ws;                                     // 4 MB
    float* sq = (float*)(ws + (size_t)NS * DD * 2);          // 32 KB
    u32* mxk = (u32*)(ws + (size_t)NS * DD * 2 + NS * 4);
    u32* mnk = mxk + NS;

    prep_kernel<<<NS * DD / 4 / 256, 256, 0, stream>>>(emb, ebf, sq, mxk, mnk, out);
    tile_kernel<<<NT, 64, 0, stream>>>(ebf, labels, mxk, mnk);
    finalize_kernel<<<NS / 256, 256, 0, stream>>>(mxk, mnk, sq, out);
}

// Round 6
// 99.250 us; speedup vs baseline: 1.1081x; 1.1081x over previous
//
#include <hip/hip_runtime.h>
#include <hip/hip_bf16.h>

// TripletBatchHardLoss: N=8192, D=256, fp32 embeddings (L2-normalized), int32 labels.
// Normalized -> pdist monotone DECREASING in dot:
//   hard_negative = max dot over negs, hard_positive = min dot over poss (diag dot~1 safe).
// R21 = PERSISTENT BLOCKS over R18's 3-buf/1-barrier/vmcnt(4) K-step.
//   - R15-R20 evidence: every concurrency structure (12 coupled / 8 coupled / 10
//     independent waves) lands 42-56us with all pipes <30%. Little's law implies
//     effective DMA latency ~5-9k cyc; an 8-step pipeline restarted 2080x spends its
//     life filling/draining. m97-GEMM (identical structure, 128-step K-loop) gets
//     MfmaUtil 37% -- the difference is pipeline DEPTH, not sync style.
//   - 768 blocks (3/CU, LDS 52KB), each owns a contiguous chunk of 2-3 tiles. The
//     3-buffer rotation + counted vmcnt(4) CONTINUE across tile boundaries: kt6/kt7 of
//     tile t prefetch kt0/kt1 of tile t+1; epilogue t overlaps t+1's in-flight DMAs.
//     Only the very last step of the last tile drains to vmcnt(0).
//   - Labels go to LDS via a size-4 global_load_lds at kt0 (1 DMA/wave, symmetric
//     vmcnt across waves; 8 steps of slack). Epilogue reads labels from LDS -> no
//     global label load at epilogue -> in-order vmcnt never force-drains prefetches.
//   - Buffer bases rotate by +2 mod 3 per tile (8%3=2) via pointer rotation, so every
//     kt's buffer pick is compile-time static (rule #20 safe).
//   - red scratch overlays lbl (4KB): lbl consumed into regs, then __syncthreads, then
//     red written -- cross-wave clobber excluded by that barrier.
// VGPR ~90 + 64 AGPR under the (256,3) cap; LDS 24+24+4 = 52KB x3 = 156KB <= 160.
// No __threadfence in wide kernels (R11: per-block fence = per-XCD L2 writeback, +130 us).

#define NS 8192
#define DD 256
#define NTILE 2080
#define NBLK 768
#define EPS_PD 1e-12f
#define BIGF 1e30f

typedef unsigned short u16;
typedef unsigned int u32;
typedef short short8 __attribute__((ext_vector_type(8)));
typedef float f32x4 __attribute__((ext_vector_type(4)));

typedef const __attribute__((address_space(1))) u32 glb_u32;
typedef __attribute__((address_space(3))) u32 lds_u32;

__device__ __forceinline__ void async16(const void* g, void* l) {
    __builtin_amdgcn_global_load_lds((glb_u32*)g, (lds_u32*)l, 16, 0, 0);
}
__device__ __forceinline__ void async4(const void* g, void* l) {
    __builtin_amdgcn_global_load_lds((glb_u32*)g, (lds_u32*)l, 4, 0, 0);
}

// order-preserving float <-> uint key (unsigned compare == float compare)
__device__ __forceinline__ u32 fkey(float f) {
    u32 b = __float_as_uint(f);
    return (b & 0x80000000u) ? ~b : (b | 0x80000000u);
}
__device__ __forceinline__ float unkey(u32 k) {
    u32 b = (k & 0x80000000u) ? (k ^ 0x80000000u) : ~k;
    return __uint_as_float(b);
}

__device__ __forceinline__ u16 f2bf_rne(float f) {
    u32 b = __float_as_uint(f);
    b += 0x7FFFu + ((b >> 16) & 1u);
    return (u16)(b >> 16);
}

// DPP lane-move within 16-lane rows (reduction groups are exactly DPP rows)
template <int CTRL>
__device__ __forceinline__ float dpp_mov(float x) {
    return __int_as_float(
        __builtin_amdgcn_update_dpp(0, __float_as_int(x), CTRL, 0xF, 0xF, true));
}

__device__ __forceinline__ void decode_tile(int t, int& bi, int& bj) {
    int j = (int)((sqrtf(8.0f * (float)t + 1.0f) - 1.0f) * 0.5f);
    while ((j + 1) * (j + 2) / 2 <= t) ++j;
    while (j * (j + 1) / 2 > t) --j;
    bi = (t - j * (j + 1) / 2) * 128;
    bj = j * 128;
}

// ---------------- kernel 1: fp32 -> bf16, row sum-of-squares, init keys ----------------
__global__ __launch_bounds__(256) void prep_kernel(
    const float* __restrict__ e, u16* __restrict__ ebf, float* __restrict__ sq,
    u32* __restrict__ mxk, u32* __restrict__ mnk, float* __restrict__ out) {
    const int tid = blockIdx.x * 256 + threadIdx.x;   // 2048 blocks
    const int row = tid >> 6, t = tid & 63;           // one wave per row
    float4 v = ((const float4*)(e + (size_t)row * DD))[t];
    ushort4 u;
    u.x = f2bf_rne(v.x); u.y = f2bf_rne(v.y); u.z = f2bf_rne(v.z); u.w = f2bf_rne(v.w);
    ((ushort4*)(ebf + (size_t)row * DD))[t] = u;
    float s = v.x * v.x + v.y * v.y + v.z * v.z + v.w * v.w;
    for (int o = 32; o; o >>= 1) s += __shfl_down(s, o);
    if (t == 0) {
        sq[row] = s;
        mxk[row] = 0u;            // sentinel for unsigned max
        mnk[row] = 0xFFFFFFFFu;   // sentinel for unsigned min
        if (row == 0) out[0] = 0.0f;
    }
}

// -------- kernel 2: persistent 3-buf triangular dot-GEMM + two-sided reduction ---------
__global__ __launch_bounds__(256, 3) void tile_kernel(
    const u16* __restrict__ ebf, const int* __restrict__ labels,
    u32* __restrict__ mxk, u32* __restrict__ mnk) {
    // 3 x (128x32) tiles each; 16B chunk (row,c) at slot row*4 + (c^((row>>2)&3))
    __shared__ __attribute__((aligned(16))) u16 sA[3][4096];   // 24 KB
    __shared__ __attribute__((aligned(16))) u16 sB[3][4096];   // 24 KB
    __shared__ __attribute__((aligned(16))) float red[1024];   // 4 KB; first 1KB doubles as lbl
    int* lbl = (int*)red;

    const int tid = threadIdx.x;
    const int lane = tid & 63, wid = tid >> 6;
    const int wm = wid >> 1, wn = wid & 1;
    const int l15 = lane & 15, q = lane >> 4;

    const int blk = blockIdx.x;
    int t = (blk * NTILE) / NBLK;
    const int tend = ((blk + 1) * NTILE) / NBLK;

    // staging lane constants: wave wid owns slots [wid*128, +128) of each 512-slot tile
    const int s0 = wid * 128 + lane, s1 = s0 + 64;
    const int r0 = s0 >> 2, c0 = (s0 & 3) ^ ((r0 >> 2) & 3);
    const int r1 = s1 >> 2, c1 = (s1 & 3) ^ ((r1 >> 2) & 3);
    const int ldst0 = wid * 128 * 8, ldst1 = ldst0 + 64 * 8;

    // frag-read offsets (u16): row = base+l15, chunk q -> slot row*4 + (q^((row>>2)&3))
    const int swz = (q ^ (l15 >> 2)) * 8;
    const int offa = (wm * 64 + l15) * 32 + swz;
    const int offb = (wn * 64 + l15) * 32 + swz;

    u16* sAf = &sA[0][0];
    u16* sBf = &sB[0][0];

    int bi, bj;
    decode_tile(t, bi, bj);
    const u16* cA0 = ebf + (size_t)(bi + r0) * DD + c0 * 8;
    const u16* cA1 = ebf + (size_t)(bi + r1) * DD + c1 * 8;
    const u16* cB0 = ebf + (size_t)(bj + r0) * DD + c0 * 8;
    const u16* cB1 = ebf + (size_t)(bj + r1) * DD + c1 * 8;

    u32 P0 = 0, P1 = 4096, P2 = 8192;   // rotating buffer bases (u16 units)

#define ISSUE4(base, pa0, pa1, pb0, pb1, ko)                  \
    do {                                                      \
        async16((pa0) + (ko), sAf + (base) + ldst0);          \
        async16((pa1) + (ko), sAf + (base) + ldst1);          \
        async16((pb0) + (ko), sBf + (base) + ldst0);          \
        async16((pb1) + (ko), sBf + (base) + ldst1);          \
    } while (0)

    // prologue: steps 0,1 of first tile (8 DMAs in flight per wave)
    ISSUE4(P0, cA0, cA1, cB0, cB1, 0);
    ISSUE4(P1, cA0, cA1, cB0, cB1, 32);

    for (; t < tend; ++t) {
        const bool hn = (t + 1 < tend);
        int nbi = bi, nbj = bj;
        const u16 *nA0 = cA0, *nA1 = cA1, *nB0 = cB0, *nB1 = cB1;
        if (hn) {
            decode_tile(t + 1, nbi, nbj);
            nA0 = ebf + (size_t)(nbi + r0) * DD + c0 * 8;
            nA1 = ebf + (size_t)(nbi + r1) * DD + c1 * 8;
            nB0 = ebf + (size_t)(nbj + r0) * DD + c0 * 8;
            nB1 = ebf + (size_t)(nbj + r1) * DD + c1 * 8;
        }

        f32x4 acc[4][4] = {};
#pragma unroll
        for (int kt = 0; kt < 8; ++kt) {
            // static buffer picks: tile-local sequence kt%3 over rotated bases
            const u32 bc = (kt % 3 == 0) ? P0 : (kt % 3 == 1) ? P1 : P2;
            const u32 bp = ((kt + 2) % 3 == 0) ? P0 : ((kt + 2) % 3 == 1) ? P1 : P2;
            // drain own step-kt batch (2-step-old issue), keep later steps in flight
            if (kt == 7 && !hn)
                asm volatile("s_waitcnt vmcnt(0)\n\ts_barrier" ::: "memory");
            else
                asm volatile("s_waitcnt vmcnt(4)\n\ts_barrier" ::: "memory");
            if (kt == 0) {
                // this tile's 256 labels -> LDS (1 size-4 DMA per wave, symmetric vmcnt)
                const int lb = (wid < 2) ? (bi + (wid & 1) * 64) : (bj + (wid & 1) * 64);
                async4(labels + lb + lane, &lbl[wid * 64]);
            }
            if (kt < 6) {
                ISSUE4(bp, cA0, cA1, cB0, cB1, (kt + 2) * 32);
            } else if (hn) {
                ISSUE4(bp, nA0, nA1, nB0, nB1, (kt - 6) * 32);
            }
            short8 af[4], bfr[4];
#pragma unroll
            for (int mi = 0; mi < 4; ++mi)
                af[mi] = *(const short8*)(sAf + bc + offa + mi * 512);
#pragma unroll
            for (int ni = 0; ni < 4; ++ni)
                bfr[ni] = *(const short8*)(sBf + bc + offb + ni * 512);
#pragma unroll
            for (int mi = 0; mi < 4; ++mi)
#pragma unroll
                for (int ni = 0; ni < 4; ++ni)
                    acc[mi][ni] = __builtin_amdgcn_mfma_f32_16x16x32_bf16(
                        af[mi], bfr[ni], acc[mi][ni], 0, 0, 0);
        }

        // ---- epilogue: C/D layout col = lane&15, row = q*4 + reg (m89-verified) ----
        // labels from LDS (DMA'd at kt0, drained by kt2's vmcnt, barrier-ordered since)
        int li[4][4];
#pragma unroll
        for (int mi = 0; mi < 4; ++mi) {
            const int4 v = *(const int4*)&lbl[wm * 64 + mi * 16 + q * 4];
            li[mi][0] = v.x; li[mi][1] = v.y; li[mi][2] = v.z; li[mi][3] = v.w;
        }
        int lj[4];
#pragma unroll
        for (int ni = 0; ni < 4; ++ni) lj[ni] = lbl[128 + wn * 64 + ni * 16 + l15];
        __syncthreads();   // all lbl reads done before red (overlapping bytes) is written

        float mxn[4][4], mnp[4][4];
        float mxc[4] = {-BIGF, -BIGF, -BIGF, -BIGF};
        float mnc[4] = {BIGF, BIGF, BIGF, BIGF};
#pragma unroll
        for (int mi = 0; mi < 4; ++mi)
#pragma unroll
            for (int r2 = 0; r2 < 4; ++r2) { mxn[mi][r2] = -BIGF; mnp[mi][r2] = BIGF; }

#pragma unroll
        for (int mi = 0; mi < 4; ++mi)
#pragma unroll
            for (int ni = 0; ni < 4; ++ni) {
                const int l = lj[ni];
#pragma unroll
                for (int r2 = 0; r2 < 4; ++r2) {
                    const float d = acc[mi][ni][r2];
                    const bool same = (li[mi][r2] == l);
                    const float sneg = same ? -BIGF : d;
                    const float spos = same ? d : BIGF;
                    mxn[mi][r2] = fmaxf(mxn[mi][r2], sneg);
                    mnp[mi][r2] = fminf(mnp[mi][r2], spos);
                    mxc[ni] = fmaxf(mxc[ni], sneg);
                    mnc[ni] = fminf(mnc[ni], spos);
                }
            }

        // col-side: reduce over q (lanes l15, +16, +32, +48) via shfl_xor 16/32
#pragma unroll
        for (int ni = 0; ni < 4; ++ni) {
            mxc[ni] = fmaxf(mxc[ni], __shfl_xor(mxc[ni], 16));
            mnc[ni] = fminf(mnc[ni], __shfl_xor(mnc[ni], 16));
            mxc[ni] = fmaxf(mxc[ni], __shfl_xor(mxc[ni], 32));
            mnc[ni] = fminf(mnc[ni], __shfl_xor(mnc[ni], 32));
        }
        // row-side: 16-lane DPP reduction (xor1, xor2, ror4, ror8)
#pragma unroll
        for (int mi = 0; mi < 4; ++mi)
#pragma unroll
            for (int r2 = 0; r2 < 4; ++r2) {
                float x = mxn[mi][r2], n = mnp[mi][r2];
                x = fmaxf(x, dpp_mov<0xB1>(x));  n = fminf(n, dpp_mov<0xB1>(n));
                x = fmaxf(x, dpp_mov<0x4E>(x));  n = fminf(n, dpp_mov<0x4E>(n));
                x = fmaxf(x, dpp_mov<0x124>(x)); n = fminf(n, dpp_mov<0x124>(n));
                x = fmaxf(x, dpp_mov<0x128>(x)); n = fminf(n, dpp_mov<0x128>(n));
                mxn[mi][r2] = x; mnp[mi][r2] = n;
            }

        // ---- block-level LDS combine -> 8 atomic wave-instrs (2 per wave) ----
        // Layout (floats): [0..255] rowmax[row][wn], [256..511] rowmin,
        // [512..767] colmax[col][wm], [768..1023] colmin.
        if (l15 == 0) {
#pragma unroll
            for (int mi = 0; mi < 4; ++mi)
#pragma unroll
                for (int r2 = 0; r2 < 4; ++r2) {
                    const int rl = wm * 64 + mi * 16 + q * 4 + r2;
                    red[rl * 2 + wn] = mxn[mi][r2];
                    red[256 + rl * 2 + wn] = mnp[mi][r2];
                }
        }
        if (q == 0) {
#pragma unroll
            for (int ni = 0; ni < 4; ++ni) {
                const int cl = wn * 64 + ni * 16 + l15;
                red[512 + cl * 2 + wm] = mxc[ni];
                red[768 + cl * 2 + wm] = mnc[ni];
            }
        }
        __syncthreads();
        if (tid < 128) {
            const float mx = fmaxf(red[tid * 2], red[tid * 2 + 1]);
            const float mn = fminf(red[256 + tid * 2], red[256 + tid * 2 + 1]);
            atomicMax(&mxk[bi + tid], fkey(mx));
            atomicMin(&mnk[bi + tid], fkey(mn));
        } else {
            const int c = tid - 128;
            const float mx = fmaxf(red[512 + c * 2], red[512 + c * 2 + 1]);
            const float mn = fminf(red[768 + c * 2], red[768 + c * 2 + 1]);
            atomicMax(&mxk[bj + c], fkey(mx));
            atomicMin(&mnk[bj + c], fkey(mn));
        }

        // rotate buffer bases by +2 mod 3 (8 steps per tile); adopt next tile's ptrs
        const u32 tp = P0; P0 = P2; P2 = P1; P1 = tp;
        bi = nbi; bj = nbj; cA0 = nA0; cA1 = nA1; cB0 = nB0; cB1 = nB1;
    }
}

// ---------------- kernel 3: per-row loss + mean ----------------
__global__ __launch_bounds__(256) void finalize_kernel(
    const u32* __restrict__ mxk, const u32* __restrict__ mnk,
    const float* __restrict__ sq, float* __restrict__ out) {
    const int i = blockIdx.x * 256 + threadIdx.x;
    const float s = sq[i] + 1.0f;   // sq_i + sq_j, sq_j = 1 +- 1e-7
    const float hn = sqrtf(fmaxf(fmaf(-2.0f, unkey(mxk[i]), s), EPS_PD));
    const float hp = sqrtf(fmaxf(fmaf(-2.0f, unkey(mnk[i]), s), EPS_PD));
    float loss = fmaxf(hp - hn + 1.0f, 0.0f);
    for (int o = 32; o; o >>= 1) loss += __shfl_down(loss, o);
    __shared__ float wsum[4];
    const int lane = threadIdx.x & 63, w = threadIdx.x >> 6;
    if (lane == 0) wsum[w] = loss;
    __syncthreads();
    if (threadIdx.x == 0)
        atomicAdd(out, (wsum[0] + wsum[1] + wsum[2] + wsum[3]) * (1.0f / NS));
}

extern "C" void kernel_launch(void* const* d_in, const int* in_sizes, int n_in,
                              void* d_out, int out_size, void* d_ws, size_t ws_size,
                              hipStream_t stream) {
    const int* labels = (const int*)d_in[0];
    const float* emb = (const float*)d_in[1];
    float* out = (float*)d_out;

    char* ws = (char*)d_ws;
    u16* ebf = (u16*)ws;                                     // 4 MB
    float* sq = (float*)(ws + (size_t)NS * DD * 2);          // 32 KB
    u32* mxk = (u32*)(ws + (size_t)NS * DD * 2 + NS * 4);
    u32* mnk = mxk + NS;

    prep_kernel<<<NS * DD / 4 / 256, 256, 0, stream>>>(emb, ebf, sq, mxk, mnk, out);
    tile_kernel<<<NBLK, 256, 0, stream>>>(ebf, labels, mxk, mnk);
    finalize_kernel<<<NS / 256, 256, 0, stream>>>(mxk, mnk, sq, out);
}